// Round 13
// baseline (366.933 us; speedup 1.0000x reference)
//
#include <hip/hip_runtime.h>
#include <hip/hip_bf16.h>
#include <stdint.h>

#define S_LEN 512
#define BATCH 512
#define HID   128
#define G3    384
#define EMB   50
#define VOC   50000

// sigmoid(x) = rcp(1 + exp2(x * -log2(e))); tanh(y) = 2*sigmoid(2y)-1.
// W_hh/gxv rows are PRE-SCALED: r,z rows by NL2E, n rows by N2L2E.
#define NL2E  (-1.4426950408889634f)
#define N2L2E (-2.8853900817779268f)

typedef __attribute__((ext_vector_type(8))) short short8;
typedef __attribute__((ext_vector_type(4))) float float4v;

__device__ inline unsigned short f2bf(float f) {
  union { float f; uint32_t u; } v; v.f = f;
  uint32_t u = v.u;
  u += 0x7fffu + ((u >> 16) & 1u);   // RNE
  return (unsigned short)(u >> 16);
}
__device__ inline float bf2f(unsigned short h) {
  union { uint32_t u; float f; } v; v.u = ((uint32_t)h) << 16;
  return v.f;
}
__device__ inline uint32_t fbits(float f) {
  union { float f; uint32_t u; } v; v.f = f; return v.u;
}
__device__ inline float fast_sig(float x) {
  return __builtin_amdgcn_rcpf(1.f + __expf(-x));
}

// ---------------------------------------------------------------------------
// Kernel A0 (tiny): pre-convert W_ih to scaled bf16 B-fragments + biases.
// Also zeroes the 128 head-handoff flags (ws is re-poisoned every launch).
// ---------------------------------------------------------------------------
__global__ __launch_bounds__(128) void prep_wih(
    const float* __restrict__ W_ih, const float* __restrict__ b_ih,
    const float* __restrict__ b_hh, unsigned short* __restrict__ wbf,
    float* __restrict__ sbias, int* __restrict__ flags) {
  const int nt = blockIdx.x;          // 0..23
  const int kf = threadIdx.x >> 6;    // 0..1
  const int L  = threadIdx.x & 63;
  const int q = L >> 4, ln = L & 15;
  const int g = nt * 16 + ln;
  const float sc = (g < 256) ? NL2E : N2L2E;
  const int k0 = kf * 32 + q * 8;
  short8 v;
#pragma unroll
  for (int i = 0; i < 8; ++i) {
    const int k = k0 + i;
    v[i] = (k < EMB) ? (short)f2bf(W_ih[(size_t)g * EMB + k] * sc) : (short)0;
  }
  *(short8*)(wbf + (size_t)((nt * 2 + kf) * 64 + L) * 8) = v;
  if (threadIdx.x < 16) {
    const int gg = nt * 16 + threadIdx.x;
    const float s2 = (gg < 256) ? NL2E : N2L2E;
    sbias[gg] = s2 * (b_ih[gg] + (gg < 256 ? b_hh[gg] : 0.f));
  }
  if (nt == 0) flags[threadIdx.x] = 0;   // 128 chunk flags
}

// ---------------------------------------------------------------------------
// Kernel A (MFMA): gxv[v][g] = sc(g) * (b_ih[g] + (g<256 ? b_hh[g] : 0)
//                              + sum_e W_ih[g][e] * emb[v][e])
// A-frags via float4 loads + lane masks (scalar fallback for last block);
// depth-1 pipelined wbf/sbias loads; C staged in LDS, bulk-stored coalesced.
// ---------------------------------------------------------------------------
__global__ __launch_bounds__(256) void build_gxv(
    const float* __restrict__ emb, const unsigned short* __restrict__ wbf,
    const float* __restrict__ sbias, unsigned short* __restrict__ gxv) {
  __shared__ __align__(16) unsigned short cmat[64][392];  // 64 vocab rows, +8 pad
  const int w  = threadIdx.x >> 6;
  const int L  = threadIdx.x & 63;
  const int q  = L >> 4;
  const int ln = L & 15;
  const int vbase = blockIdx.x * 64 + w * 16;
  const int vloc  = w * 16;
  const int nblocks = (VOC + 63) / 64;

  const int vr = min(vbase + ln, VOC - 1);
  const float* arow = emb + (size_t)vr * EMB;
  short8 afr0, afr1;
  if (blockIdx.x != nblocks - 1) {
    const float4v x0 = *(const float4v*)(arow + q * 8);
    const float4v x1 = *(const float4v*)(arow + q * 8 + 4);
    const float4v y0 = *(const float4v*)(arow + 32 + q * 8);
    const float4v y1 = *(const float4v*)(arow + 32 + q * 8 + 4);
#pragma unroll
    for (int i = 0; i < 4; ++i) {
      afr0[i]     = (short)f2bf(x0[i]);
      afr0[i + 4] = (short)f2bf(x1[i]);
      const int ky0 = 32 + q * 8 + i, ky1 = ky0 + 4;
      afr1[i]     = (ky0 < EMB) ? (short)f2bf(y0[i]) : (short)0;
      afr1[i + 4] = (ky1 < EMB) ? (short)f2bf(y1[i]) : (short)0;
    }
  } else {
    float f;
#pragma unroll
    for (int i = 0; i < 8; ++i) {
      const int k = q * 8 + i; f = (k < EMB) ? arow[k] : 0.f;
      afr0[i] = (short)f2bf(f);
    }
#pragma unroll
    for (int i = 0; i < 8; ++i) {
      const int k = 32 + q * 8 + i; f = (k < EMB) ? arow[k] : 0.f;
      afr1[i] = (short)f2bf(f);
    }
  }

  short8 b0 = *(const short8*)(wbf + (size_t)(0 * 64 + L) * 8);
  short8 b1 = *(const short8*)(wbf + (size_t)(1 * 64 + L) * 8);
  float bias = sbias[ln];
  for (int nt = 0; nt < 24; ++nt) {
    short8 nb0, nb1; float nbias;
    if (nt < 23) {
      nb0 = *(const short8*)(wbf + (size_t)((nt * 2 + 2) * 64 + L) * 8);
      nb1 = *(const short8*)(wbf + (size_t)((nt * 2 + 3) * 64 + L) * 8);
      nbias = sbias[nt * 16 + 16 + ln];
    }
    const int gg = nt * 16 + ln;
    float4v acc = {bias, bias, bias, bias};
    acc = __builtin_amdgcn_mfma_f32_16x16x32_bf16(afr0, b0, acc, 0, 0, 0);
    acc = __builtin_amdgcn_mfma_f32_16x16x32_bf16(afr1, b1, acc, 0, 0, 0);
#pragma unroll
    for (int r = 0; r < 4; ++r)
      cmat[vloc + q * 4 + r][gg] = f2bf(acc[r]);
    b0 = nb0; b1 = nb1; bias = nbias;
  }
  __syncthreads();

  for (int idx = threadIdx.x; idx < 3072; idx += 256) {
    const int row = idx / 48, c8 = idx - row * 48;
    const int vrow = blockIdx.x * 64 + row;
    if (vrow < VOC) {
      short8 v = *(const short8*)(&cmat[row][c8 * 8]);
      *(short8*)(gxv + (size_t)vrow * G3 + c8 * 8) = v;
    }
  }
}

// ---------------------------------------------------------------------------
// Kernel B: persistent GRU recurrence — loop is the EXACT R7 schedule
// (proven optimum; R8/R9/R10/R11 variants all regressed or failed).
// R13 adds a TAIL: the pair of blocks (gru0,c),(gru1,c) covers batch
// 4c..4c+3; the last-arriving block (device-scope atomicAdd on flags[c],
// release/acquire via __threadfence — required across XCD L2s) computes the
// MLP head for those 4 batch elements, eliminating the head_kernel node.
// ---------------------------------------------------------------------------
__global__ __launch_bounds__(512) void gru_kernel(
    const int* __restrict__ x1, const int* __restrict__ x2,
    const unsigned short* __restrict__ gxv, const float* __restrict__ W_hh,
    const float* __restrict__ b_hh, float* __restrict__ fcin,
    int* __restrict__ flags, const float* __restrict__ W1,
    const float* __restrict__ b1, const float* __restrict__ W2,
    const float* __restrict__ b2, float* __restrict__ out) {
  const int bid   = blockIdx.x;
  const int gru   = bid >> 7;         // 0..1
  const int chunk = bid & 127;        // 0..127
  const int* xs   = gru ? x2 : x1;

  const int tid = threadIdx.x;
  const int w  = tid >> 6;            // wave 0..7
  const int L  = tid & 63;            // lane
  const int q  = L >> 4;              // C-layout quad
  const int ln = L & 15;              // C-layout col group
  const int jb = w * 16;
  const int g3 = ln >> 2;             // which C register this lane consumes
  const int n  = ln & 3;              // batch column (0..3)
  const int j  = jb + q * 4 + g3;     // this lane's hidden unit
  const int ng = chunk * 4 + n;       // global batch index

  __shared__ __align__(16) unsigned short hbuf[2][512]; // h^T packed B-frags

  // --- resident A fragments (pre-scaled): A[m=ln][k=q*8+i] per 16x16x32 ---
  short8 afrag[3][4];
#pragma unroll
  for (int t = 0; t < 3; ++t) {
    const float sc = (t < 2) ? NL2E : N2L2E;
    const float* wr = W_hh + (size_t)(t * 128 + jb + ln) * HID;
#pragma unroll
    for (int kf = 0; kf < 4; ++kf) {
      const int k0 = kf * 32 + q * 8;
      float4v f0 = *(const float4v*)(wr + k0);
      float4v f1 = *(const float4v*)(wr + k0 + 4);
      short8 a;
#pragma unroll
      for (int i = 0; i < 4; ++i) a[i] = (short)f2bf(f0[i] * sc);
#pragma unroll
      for (int i = 0; i < 4; ++i) a[i + 4] = (short)f2bf(f1[i] * sc);
      afrag[t][kf] = a;
    }
  }

  // n-gate C-init: bhn * N2L2E per C row (row r -> j = jb + q*4 + r)
  float4v bhn4;
#pragma unroll
  for (int r = 0; r < 4; ++r) bhn4[r] = N2L2E * b_hh[2 * 128 + jb + q * 4 + r];

  // zero both h buffers (h0 = 0)
  for (int idx = tid; idx < 1024; idx += 512) ((unsigned short*)hbuf)[idx] = 0;

  float h = 0.f;

  // gx prefetch depth 2: 3 bf16 scalars per lane-step
  unsigned short cr, cz, cn, mr, mz, mn;
  {
    const unsigned short* gp = gxv + (size_t)xs[ng] * G3;
    cr = gp[j]; cz = gp[128 + j]; cn = gp[256 + j];
    const unsigned short* gq = gxv + (size_t)xs[BATCH + ng] * G3;
    mr = gq[j]; mz = gq[128 + j]; mn = gq[256 + j];
  }
  int tokf = xs[2 * BATCH + ng];      // token for s+2

  // h' write offset in packed B-frag order: ((j>>3)*4 + n)*8 + (j&7)
  const int wofs = (((j >> 3) * 4 + n) << 3) + (j & 7);
  // B-frag read offset: cols >=4 alias col&3 (LDS same-address broadcast)
  const int rofs = ((q * 4 + n) << 3);

  const bool selA = (ln & 4) != 0;    // g3 bit 0
  const bool selB = (ln & 8) != 0;    // g3 bit 1

  __syncthreads();

  for (int s = 0; s < S_LEN; ++s) {
    // issue gx for step s+2 (stays in flight across two lgkm-only barriers)
    unsigned short fr, fz, fn;
    {
      const unsigned short* gp = gxv + (size_t)tokf * G3;
      fr = gp[j]; fz = gp[128 + j]; fn = gp[256 + j];
    }
    const int s3 = (s + 3 < S_LEN) ? (s + 3) : 0;   // uniform clamp
    const int tok3 = xs[s3 * BATCH + ng];

    // B fragments from packed h^T buffer
    const unsigned short* rb = hbuf[s & 1];
    short8 bfrag[4];
#pragma unroll
    for (int kf = 0; kf < 4; ++kf)
      bfrag[kf] = *(const short8*)(rb + kf * 128 + rofs);

    // 2 independent 2-deep MFMA chains per gate; n-gate C-init = scaled bhn
    float vsel[3];
#pragma unroll
    for (int t = 0; t < 3; ++t) {
      float4v a0 = (t == 2) ? bhn4 : (float4v){0.f, 0.f, 0.f, 0.f};
      float4v a1 = {0.f, 0.f, 0.f, 0.f};
      a0 = __builtin_amdgcn_mfma_f32_16x16x32_bf16(afrag[t][0], bfrag[0], a0, 0, 0, 0);
      a1 = __builtin_amdgcn_mfma_f32_16x16x32_bf16(afrag[t][1], bfrag[1], a1, 0, 0, 0);
      a0 = __builtin_amdgcn_mfma_f32_16x16x32_bf16(afrag[t][2], bfrag[2], a0, 0, 0, 0);
      a1 = __builtin_amdgcn_mfma_f32_16x16x32_bf16(afrag[t][3], bfrag[3], a1, 0, 0, 0);
      const float4v acc = a0 + a1;
      // per-lane register select: r = g3 (C redundancy across ln-groups)
      const float x0 = selA ? acc[1] : acc[0];
      const float x1 = selA ? acc[3] : acc[2];
      vsel[t] = selB ? x1 : x0;
    }

    // gate math (args pre-scaled by -log2e / -2log2e): 1 elem per lane
    const float gr = bf2f(cr) + vsel[0];
    const float gz = bf2f(cz) + vsel[1];
    const float rg = __builtin_amdgcn_rcpf(1.f + __builtin_amdgcn_exp2f(gr));
    const float zg = __builtin_amdgcn_rcpf(1.f + __builtin_amdgcn_exp2f(gz));
    const float pre = bf2f(cn) + rg * vsel[2];
    const float sg  = __builtin_amdgcn_rcpf(1.f + __builtin_amdgcn_exp2f(pre));
    const float nn  = 2.f * sg - 1.f;                // tanh
    h = zg * (h - nn) + nn;

    // write h' as bf16 (round-half-up): one b16 write, all 64 lanes
    hbuf[(s + 1) & 1][wofs] = (unsigned short)((fbits(h) + 0x8000u) >> 16);

    // LDS-only barrier: do NOT drain vmcnt — gx prefetches stay in flight
    asm volatile("s_waitcnt lgkmcnt(0)\n\ts_barrier" ::: "memory");

    cr = mr; cz = mz; cn = mn;
    mr = fr; mz = fz; mn = fn;
    tokf = tok3;
  }

  // final h -> fcin[b][gru*128 + j]
  fcin[(size_t)ng * 256 + gru * 128 + j] = h;

  // ---- head handoff: last-arriving block of the (gru0,c)/(gru1,c) pair ----
  __shared__ int do_head;
  __syncthreads();                       // drains vmcnt: fcin stores in L2
  if (tid == 0) {
    __threadfence();                     // release: L2 writeback (cross-XCD)
    do_head = (atomicAdd(&flags[chunk], 1) == 1);
  }
  __syncthreads();
  if (!do_head) return;
  __threadfence();                       // acquire: writeback + invalidate

  // head for batch b = 4c..4c+3: 512 threads = 4 b x 128 hidden units
  __shared__ __align__(16) float fcs[4][256];
  __shared__ float part[8];
  for (int idx = tid; idx < 1024; idx += 512)
    fcs[idx >> 8][idx & 255] = fcin[(size_t)(chunk * 4 + (idx >> 8)) * 256 + (idx & 255)];
  __syncthreads();

  const int bl = tid >> 7;               // batch-local 0..3
  const int tt = tid & 127;              // hidden unit
  float acc = b1[tt];
  const float4v* wr  = (const float4v*)(W1 + (size_t)tt * 256);
  const float4v* fc4 = (const float4v*)fcs[bl];
#pragma unroll 8
  for (int k = 0; k < 64; ++k) {
    const float4v wv = wr[k];
    const float4v fv = fc4[k];
    acc += wv[0] * fv[0] + wv[1] * fv[1] + wv[2] * fv[2] + wv[3] * fv[3];
  }
  const float hid = fmaxf(acc, 0.f);

  float v = hid * W2[tt];
#pragma unroll
  for (int o = 32; o > 0; o >>= 1) v += __shfl_xor(v, o, 64);
  if ((tid & 63) == 0) part[tid >> 6] = v;   // 2 waves per b
  __syncthreads();
  if (tt == 0)
    out[chunk * 4 + bl] = fast_sig(part[2 * bl] + part[2 * bl + 1] + b2[0]);
}

// ---------------------------------------------------------------------------
extern "C" void kernel_launch(void* const* d_in, const int* in_sizes, int n_in,
                              void* d_out, int out_size, void* d_ws, size_t ws_size,
                              hipStream_t stream) {
  const int*   x1   = (const int*)d_in[0];
  const int*   x2   = (const int*)d_in[1];
  const float* emb  = (const float*)d_in[2];
  const float* W_ih = (const float*)d_in[3];
  const float* W_hh = (const float*)d_in[4];
  const float* b_ih = (const float*)d_in[5];
  const float* b_hh = (const float*)d_in[6];
  const float* W1   = (const float*)d_in[7];
  const float* b1   = (const float*)d_in[8];
  const float* W2   = (const float*)d_in[9];
  const float* b2   = (const float*)d_in[10];
  float* out = (float*)d_out;

  char* ws = (char*)d_ws;
  unsigned short* gxv  = (unsigned short*)ws;                     // 38.4 MB
  float*          fcin = (float*)(ws + (size_t)VOC * G3 * 2);     // 512 KB
  unsigned short* wbf  = (unsigned short*)(ws + (size_t)VOC * G3 * 2 + 524288); // 48 KB
  float*          sbias= (float*)(ws + (size_t)VOC * G3 * 2 + 524288 + 49152);  // 1.5 KB
  int*            flags= (int*)(ws + (size_t)VOC * G3 * 2 + 524288 + 49152 + 1536); // 512 B

  prep_wih<<<24, 128, 0, stream>>>(W_ih, b_ih, b_hh, wbf, sbias, flags);
  build_gxv<<<(VOC + 63) / 64, 256, 0, stream>>>(emb, wbf, sbias, gxv);
  gru_kernel<<<256, 512, 0, stream>>>(x1, x2, gxv, W_hh, b_hh, fcin,
                                      flags, W1, b1, W2, b2, out);
}

// Round 14
// 341.924 us; speedup vs baseline: 1.0731x; 1.0731x over previous
//
#include <hip/hip_runtime.h>
#include <hip/hip_bf16.h>
#include <stdint.h>

#define S_LEN 512
#define BATCH 512
#define HID   128
#define G3    384
#define EMB   50
#define VOC   50000

// sigmoid(x) = rcp(1 + exp2(x * -log2(e))); tanh(y) = 2*sigmoid(2y)-1.
// W_hh/gxv rows are PRE-SCALED: r,z rows by NL2E, n rows by N2L2E.
#define NL2E  (-1.4426950408889634f)
#define N2L2E (-2.8853900817779268f)

typedef __attribute__((ext_vector_type(8))) short short8;
typedef __attribute__((ext_vector_type(4))) float float4v;

__device__ inline unsigned short f2bf(float f) {
  union { float f; uint32_t u; } v; v.f = f;
  uint32_t u = v.u;
  u += 0x7fffu + ((u >> 16) & 1u);   // RNE
  return (unsigned short)(u >> 16);
}
__device__ inline float bf2f(unsigned short h) {
  union { uint32_t u; float f; } v; v.u = ((uint32_t)h) << 16;
  return v.f;
}
__device__ inline uint32_t fbits(float f) {
  union { float f; uint32_t u; } v; v.f = f; return v.u;
}
__device__ inline float fast_sig(float x) {
  return __builtin_amdgcn_rcpf(1.f + __expf(-x));
}

// ---------------------------------------------------------------------------
// Kernel A0 (tiny): pre-convert W_ih to scaled bf16 B-fragments + biases.
// ---------------------------------------------------------------------------
__global__ __launch_bounds__(128) void prep_wih(
    const float* __restrict__ W_ih, const float* __restrict__ b_ih,
    const float* __restrict__ b_hh, unsigned short* __restrict__ wbf,
    float* __restrict__ sbias) {
  const int nt = blockIdx.x;          // 0..23
  const int kf = threadIdx.x >> 6;    // 0..1
  const int L  = threadIdx.x & 63;
  const int q = L >> 4, ln = L & 15;
  const int g = nt * 16 + ln;
  const float sc = (g < 256) ? NL2E : N2L2E;
  const int k0 = kf * 32 + q * 8;
  short8 v;
#pragma unroll
  for (int i = 0; i < 8; ++i) {
    const int k = k0 + i;
    v[i] = (k < EMB) ? (short)f2bf(W_ih[(size_t)g * EMB + k] * sc) : (short)0;
  }
  *(short8*)(wbf + (size_t)((nt * 2 + kf) * 64 + L) * 8) = v;
  if (threadIdx.x < 16) {
    const int gg = nt * 16 + threadIdx.x;
    const float s2 = (gg < 256) ? NL2E : N2L2E;
    sbias[gg] = s2 * (b_ih[gg] + (gg < 256 ? b_hh[gg] : 0.f));
  }
}

// ---------------------------------------------------------------------------
// Kernel A (MFMA): gxv[v][g] = sc(g) * (b_ih[g] + (g<256 ? b_hh[g] : 0)
//                              + sum_e W_ih[g][e] * emb[v][e])
// A-frags via float4 loads + lane masks (scalar fallback for last block);
// depth-1 pipelined wbf/sbias loads; C staged in LDS, bulk-stored coalesced.
// ---------------------------------------------------------------------------
__global__ __launch_bounds__(256) void build_gxv(
    const float* __restrict__ emb, const unsigned short* __restrict__ wbf,
    const float* __restrict__ sbias, unsigned short* __restrict__ gxv) {
  __shared__ __align__(16) unsigned short cmat[64][392];  // 64 vocab rows, +8 pad
  const int w  = threadIdx.x >> 6;
  const int L  = threadIdx.x & 63;
  const int q  = L >> 4;
  const int ln = L & 15;
  const int vbase = blockIdx.x * 64 + w * 16;
  const int vloc  = w * 16;
  const int nblocks = (VOC + 63) / 64;

  const int vr = min(vbase + ln, VOC - 1);
  const float* arow = emb + (size_t)vr * EMB;
  short8 afr0, afr1;
  if (blockIdx.x != nblocks - 1) {
    const float4v x0 = *(const float4v*)(arow + q * 8);
    const float4v x1 = *(const float4v*)(arow + q * 8 + 4);
    const float4v y0 = *(const float4v*)(arow + 32 + q * 8);
    const float4v y1 = *(const float4v*)(arow + 32 + q * 8 + 4);
#pragma unroll
    for (int i = 0; i < 4; ++i) {
      afr0[i]     = (short)f2bf(x0[i]);
      afr0[i + 4] = (short)f2bf(x1[i]);
      const int ky0 = 32 + q * 8 + i, ky1 = ky0 + 4;
      afr1[i]     = (ky0 < EMB) ? (short)f2bf(y0[i]) : (short)0;
      afr1[i + 4] = (ky1 < EMB) ? (short)f2bf(y1[i]) : (short)0;
    }
  } else {
    float f;
#pragma unroll
    for (int i = 0; i < 8; ++i) {
      const int k = q * 8 + i; f = (k < EMB) ? arow[k] : 0.f;
      afr0[i] = (short)f2bf(f);
    }
#pragma unroll
    for (int i = 0; i < 8; ++i) {
      const int k = 32 + q * 8 + i; f = (k < EMB) ? arow[k] : 0.f;
      afr1[i] = (short)f2bf(f);
    }
  }

  short8 b0 = *(const short8*)(wbf + (size_t)(0 * 64 + L) * 8);
  short8 b1 = *(const short8*)(wbf + (size_t)(1 * 64 + L) * 8);
  float bias = sbias[ln];
  for (int nt = 0; nt < 24; ++nt) {
    short8 nb0, nb1; float nbias;
    if (nt < 23) {
      nb0 = *(const short8*)(wbf + (size_t)((nt * 2 + 2) * 64 + L) * 8);
      nb1 = *(const short8*)(wbf + (size_t)((nt * 2 + 3) * 64 + L) * 8);
      nbias = sbias[nt * 16 + 16 + ln];
    }
    const int gg = nt * 16 + ln;
    float4v acc = {bias, bias, bias, bias};
    acc = __builtin_amdgcn_mfma_f32_16x16x32_bf16(afr0, b0, acc, 0, 0, 0);
    acc = __builtin_amdgcn_mfma_f32_16x16x32_bf16(afr1, b1, acc, 0, 0, 0);
#pragma unroll
    for (int r = 0; r < 4; ++r)
      cmat[vloc + q * 4 + r][gg] = f2bf(acc[r]);
    b0 = nb0; b1 = nb1; bias = nbias;
  }
  __syncthreads();

  for (int idx = threadIdx.x; idx < 3072; idx += 256) {
    const int row = idx / 48, c8 = idx - row * 48;
    const int vrow = blockIdx.x * 64 + row;
    if (vrow < VOC) {
      short8 v = *(const short8*)(&cmat[row][c8 * 8]);
      *(short8*)(gxv + (size_t)vrow * G3 + c8 * 8) = v;
    }
  }
}

// ---------------------------------------------------------------------------
// Kernel B: persistent GRU recurrence — EXACT R7/R12 loop (proven optimum).
// 256 blocks = 2 GRUs x 128 chunks of FOUR batch columns -> 1 block/CU.
// 8 waves; wave w owns j in [16w,16w+16); 12 mfma_f32_16x16x32_bf16 per
// wave-step; B cols 4..15 broadcast-alias cols 0..3 -> C 4x redundant ->
// per-lane cndmask select; 1 gate elem/lane (6 transcendentals); h fp32;
// h' one ds_write_b16; lgkm-only barrier; depth-2 gx prefetch.
// DO NOT perturb this kernel in any way: R8 (unroll/plane-split), R9
// (4 waves), R10 (C-init dataflow), R11 (i8), R13 (fused head tail) ALL
// regressed its compiled loop by 15-60 us. Even tail-only additions change
// the loop's scheduling.
// ---------------------------------------------------------------------------
__global__ __launch_bounds__(512) void gru_kernel(
    const int* __restrict__ x1, const int* __restrict__ x2,
    const unsigned short* __restrict__ gxv, const float* __restrict__ W_hh,
    const float* __restrict__ b_hh, float* __restrict__ fcin) {
  const int bid   = blockIdx.x;
  const int gru   = bid >> 7;         // 0..1
  const int chunk = bid & 127;        // 0..127
  const int* xs   = gru ? x2 : x1;

  const int tid = threadIdx.x;
  const int w  = tid >> 6;            // wave 0..7
  const int L  = tid & 63;            // lane
  const int q  = L >> 4;              // C-layout quad
  const int ln = L & 15;              // C-layout col group
  const int jb = w * 16;
  const int g3 = ln >> 2;             // which C register this lane consumes
  const int n  = ln & 3;              // batch column (0..3)
  const int j  = jb + q * 4 + g3;     // this lane's hidden unit
  const int ng = chunk * 4 + n;       // global batch index

  __shared__ __align__(16) unsigned short hbuf[2][512]; // h^T packed B-frags

  // --- resident A fragments (pre-scaled): A[m=ln][k=q*8+i] per 16x16x32 ---
  short8 afrag[3][4];
#pragma unroll
  for (int t = 0; t < 3; ++t) {
    const float sc = (t < 2) ? NL2E : N2L2E;
    const float* wr = W_hh + (size_t)(t * 128 + jb + ln) * HID;
#pragma unroll
    for (int kf = 0; kf < 4; ++kf) {
      const int k0 = kf * 32 + q * 8;
      float4v f0 = *(const float4v*)(wr + k0);
      float4v f1 = *(const float4v*)(wr + k0 + 4);
      short8 a;
#pragma unroll
      for (int i = 0; i < 4; ++i) a[i] = (short)f2bf(f0[i] * sc);
#pragma unroll
      for (int i = 0; i < 4; ++i) a[i + 4] = (short)f2bf(f1[i] * sc);
      afrag[t][kf] = a;
    }
  }

  // n-gate C-init: bhn * N2L2E per C row (row r -> j = jb + q*4 + r)
  float4v bhn4;
#pragma unroll
  for (int r = 0; r < 4; ++r) bhn4[r] = N2L2E * b_hh[2 * 128 + jb + q * 4 + r];

  // zero both h buffers (h0 = 0)
  for (int idx = tid; idx < 1024; idx += 512) ((unsigned short*)hbuf)[idx] = 0;

  float h = 0.f;

  // gx prefetch depth 2: 3 bf16 scalars per lane-step
  unsigned short cr, cz, cn, mr, mz, mn;
  {
    const unsigned short* gp = gxv + (size_t)xs[ng] * G3;
    cr = gp[j]; cz = gp[128 + j]; cn = gp[256 + j];
    const unsigned short* gq = gxv + (size_t)xs[BATCH + ng] * G3;
    mr = gq[j]; mz = gq[128 + j]; mn = gq[256 + j];
  }
  int tokf = xs[2 * BATCH + ng];      // token for s+2

  // h' write offset in packed B-frag order: ((j>>3)*4 + n)*8 + (j&7)
  const int wofs = (((j >> 3) * 4 + n) << 3) + (j & 7);
  // B-frag read offset: cols >=4 alias col&3 (LDS same-address broadcast)
  const int rofs = ((q * 4 + n) << 3);

  const bool selA = (ln & 4) != 0;    // g3 bit 0
  const bool selB = (ln & 8) != 0;    // g3 bit 1

  __syncthreads();

  for (int s = 0; s < S_LEN; ++s) {
    // issue gx for step s+2 (stays in flight across two lgkm-only barriers)
    unsigned short fr, fz, fn;
    {
      const unsigned short* gp = gxv + (size_t)tokf * G3;
      fr = gp[j]; fz = gp[128 + j]; fn = gp[256 + j];
    }
    const int s3 = (s + 3 < S_LEN) ? (s + 3) : 0;   // uniform clamp
    const int tok3 = xs[s3 * BATCH + ng];

    // B fragments from packed h^T buffer
    const unsigned short* rb = hbuf[s & 1];
    short8 bfrag[4];
#pragma unroll
    for (int kf = 0; kf < 4; ++kf)
      bfrag[kf] = *(const short8*)(rb + kf * 128 + rofs);

    // 2 independent 2-deep MFMA chains per gate; n-gate C-init = scaled bhn
    float vsel[3];
#pragma unroll
    for (int t = 0; t < 3; ++t) {
      float4v a0 = (t == 2) ? bhn4 : (float4v){0.f, 0.f, 0.f, 0.f};
      float4v a1 = {0.f, 0.f, 0.f, 0.f};
      a0 = __builtin_amdgcn_mfma_f32_16x16x32_bf16(afrag[t][0], bfrag[0], a0, 0, 0, 0);
      a1 = __builtin_amdgcn_mfma_f32_16x16x32_bf16(afrag[t][1], bfrag[1], a1, 0, 0, 0);
      a0 = __builtin_amdgcn_mfma_f32_16x16x32_bf16(afrag[t][2], bfrag[2], a0, 0, 0, 0);
      a1 = __builtin_amdgcn_mfma_f32_16x16x32_bf16(afrag[t][3], bfrag[3], a1, 0, 0, 0);
      const float4v acc = a0 + a1;
      // per-lane register select: r = g3 (C redundancy across ln-groups)
      const float x0 = selA ? acc[1] : acc[0];
      const float x1 = selA ? acc[3] : acc[2];
      vsel[t] = selB ? x1 : x0;
    }

    // gate math (args pre-scaled by -log2e / -2log2e): 1 elem per lane
    const float gr = bf2f(cr) + vsel[0];
    const float gz = bf2f(cz) + vsel[1];
    const float rg = __builtin_amdgcn_rcpf(1.f + __builtin_amdgcn_exp2f(gr));
    const float zg = __builtin_amdgcn_rcpf(1.f + __builtin_amdgcn_exp2f(gz));
    const float pre = bf2f(cn) + rg * vsel[2];
    const float sg  = __builtin_amdgcn_rcpf(1.f + __builtin_amdgcn_exp2f(pre));
    const float nn  = 2.f * sg - 1.f;                // tanh
    h = zg * (h - nn) + nn;

    // write h' as bf16 (round-half-up): one b16 write, all 64 lanes
    hbuf[(s + 1) & 1][wofs] = (unsigned short)((fbits(h) + 0x8000u) >> 16);

    // LDS-only barrier: do NOT drain vmcnt — gx prefetches stay in flight
    asm volatile("s_waitcnt lgkmcnt(0)\n\ts_barrier" ::: "memory");

    cr = mr; cz = mz; cn = mn;
    mr = fr; mz = fz; mn = fn;
    tokf = tok3;
  }

  // final h -> fcin[b][gru*128 + j]
  fcin[(size_t)ng * 256 + gru * 128 + j] = h;
}

// ---------------------------------------------------------------------------
// Kernel C: out[b] = sigmoid(b2 + W2 . relu(b1 + W1 . fcin[b]))
// W1 row read via float4 (64 loads/thread).
// ---------------------------------------------------------------------------
__global__ __launch_bounds__(128) void head_kernel(
    const float* __restrict__ fcin, const float* __restrict__ W1,
    const float* __restrict__ b1, const float* __restrict__ W2,
    const float* __restrict__ b2, float* __restrict__ out) {
  __shared__ __align__(16) float fc[256];
  __shared__ float part[2];
  const int b = blockIdx.x, t = threadIdx.x;
  fc[t]       = fcin[(size_t)b * 256 + t];
  fc[t + 128] = fcin[(size_t)b * 256 + t + 128];
  __syncthreads();

  float acc = b1[t];
  const float4v* wr  = (const float4v*)(W1 + (size_t)t * 256);
  const float4v* fc4 = (const float4v*)fc;
#pragma unroll 8
  for (int k = 0; k < 64; ++k) {
    const float4v wv = wr[k];
    const float4v fv = fc4[k];
    acc += wv[0] * fv[0] + wv[1] * fv[1] + wv[2] * fv[2] + wv[3] * fv[3];
  }
  const float hid = fmaxf(acc, 0.f);

  float v = hid * W2[t];
#pragma unroll
  for (int o = 32; o > 0; o >>= 1) v += __shfl_xor(v, o, 64);
  if ((t & 63) == 0) part[t >> 6] = v;
  __syncthreads();
  if (t == 0) {
    const float s = part[0] + part[1] + b2[0];
    out[b] = fast_sig(s);
  }
}

// ---------------------------------------------------------------------------
extern "C" void kernel_launch(void* const* d_in, const int* in_sizes, int n_in,
                              void* d_out, int out_size, void* d_ws, size_t ws_size,
                              hipStream_t stream) {
  const int*   x1   = (const int*)d_in[0];
  const int*   x2   = (const int*)d_in[1];
  const float* emb  = (const float*)d_in[2];
  const float* W_ih = (const float*)d_in[3];
  const float* W_hh = (const float*)d_in[4];
  const float* b_ih = (const float*)d_in[5];
  const float* b_hh = (const float*)d_in[6];
  const float* W1   = (const float*)d_in[7];
  const float* b1   = (const float*)d_in[8];
  const float* W2   = (const float*)d_in[9];
  const float* b2   = (const float*)d_in[10];
  float* out = (float*)d_out;

  char* ws = (char*)d_ws;
  unsigned short* gxv  = (unsigned short*)ws;                     // 38.4 MB
  float*          fcin = (float*)(ws + (size_t)VOC * G3 * 2);     // 512 KB
  unsigned short* wbf  = (unsigned short*)(ws + (size_t)VOC * G3 * 2 + 524288); // 48 KB
  float*          sbias= (float*)(ws + (size_t)VOC * G3 * 2 + 524288 + 49152);  // 1.5 KB

  prep_wih<<<24, 128, 0, stream>>>(W_ih, b_ih, b_hh, wbf, sbias);
  build_gxv<<<(VOC + 63) / 64, 256, 0, stream>>>(emb, wbf, sbias, gxv);
  gru_kernel<<<256, 512, 0, stream>>>(x1, x2, gxv, W_hh, b_hh, fcin);
  head_kernel<<<512, 128, 0, stream>>>(fcin, W1, b1, W2, b2, out);
}